// Round 9
// baseline (133.609 us; speedup 1.0000x reference)
//
#include <hip/hip_runtime.h>
#include <math.h>

#define N_IN  96
#define N_OUT 192
#define BW    24    // truncated band window width
#define SP2   72    // LDS row stride in halfs (144B: 16B-aligned, 4-bank row skew)

typedef _Float16 h2 __attribute__((ext_vector_type(2)));

__device__ __forceinline__ float dot2h(unsigned int w, unsigned int v, float acc) {
#if __has_builtin(__builtin_amdgcn_fdot2)
    return __builtin_amdgcn_fdot2(__builtin_bit_cast(h2, w),
                                  __builtin_bit_cast(h2, v), acc, false);
#else
    h2 a = __builtin_bit_cast(h2, w), b = __builtin_bit_cast(h2, v);
    return acc + (float)a.x * (float)b.x + (float)a.y * (float)b.y;
#endif
}

__device__ __forceinline__ unsigned int packh2(float a, float b) {
    h2 h; h.x = (_Float16)a; h.y = (_Float16)b;
    return __builtin_bit_cast(unsigned int, h);
}

__device__ __forceinline__ void fma4(float4& a, float w, const float4& v) {
    a.x += w * v.x; a.y += w * v.y; a.z += w * v.z; a.w += w * v.w;
}

// ---------------- compile-time weight tables ----------------
// M = B_resize(192x96) * A^-1, A = cubic-spline interp operator with dct2
// boundary (tridiag: diag 2/3, 5/6 at ends, off-diag 1/6). Constexpr Thomas
// solve; stage-B weights pre-packed to half2 u32 at COMPILE TIME (no runtime
// pack -> no persistent weight registers -> VGPR fits 6 waves/SIMD).
struct Tables {
    float        WB8T[24][24][8];   // pass-x: [oct][tap][jj], window S8[oct]
    float        WB4 [48][24][4];   // stage-A: [j-quad][tap][jj], window S8
    unsigned int WT12[192][12];     // stage-B: [j][tap-pair] half2, window S4[j/4]
    int          S8[24];
    int          S4[48];
};

constexpr int cfold(int idx, int n) {
    int p = 2 * n;
    int m = idx % p; if (m < 0) m += p;
    return (m >= n) ? (p - 1 - m) : m;
}

constexpr unsigned int cpackh2(double a, double b) {
    _Float16 ha = (_Float16)(float)a;   // match runtime double->float->half path
    _Float16 hb = (_Float16)(float)b;
    unsigned short ua = __builtin_bit_cast(unsigned short, ha);
    unsigned short ub = __builtin_bit_cast(unsigned short, hb);
    return (unsigned int)ua | ((unsigned int)ub << 16);
}

constexpr Tables make_tables() {
    Tables T{};
    double cp[N_IN] = {}, minv[N_IN] = {};
    const double a = 1.0 / 6.0;
    minv[0] = 1.0 / (5.0 / 6.0);
    cp[0]   = a * minv[0];
    for (int i = 1; i < N_IN; ++i) {
        double bi = (i == N_IN - 1) ? (5.0 / 6.0) : (2.0 / 3.0);
        minv[i] = 1.0 / (bi - a * cp[i - 1]);
        cp[i]   = a * minv[i];
    }
    for (int j = 0; j < N_OUT; ++j) {
        double x = (double)j * 95.0 / 191.0;
        int    b = (int)x;
        double t = x - (double)b;
        double t2 = t * t, t3 = t2 * t;
        double w0 = (1.0 - t) * (1.0 - t) * (1.0 - t) / 6.0;
        double w1 = (3.0 * t3 - 6.0 * t2 + 4.0) / 6.0;
        double w2 = (-3.0 * t3 + 3.0 * t2 + 3.0 * t + 1.0) / 6.0;
        double w3 = t3 / 6.0;
        double r[N_IN] = {};
        r[cfold(b - 1, N_IN)] += w0;
        r[cfold(b,     N_IN)] += w1;
        r[cfold(b + 1, N_IN)] += w2;
        r[cfold(b + 2, N_IN)] += w3;
        double m[N_IN] = {};
        double dp = 0.0;
        for (int i = 0; i < N_IN; ++i) {
            dp = (i == 0) ? r[0] * minv[0] : (r[i] - a * dp) * minv[i];
            m[i] = dp;
        }
        double xv = 0.0;
        for (int i = N_IN - 1; i >= 0; --i) {
            xv = (i == N_IN - 1) ? m[i] : (m[i] - cp[i] * xv);
            m[i] = xv;
        }
        int s8 = ((j & ~7) * 95) / 191 - 9;
        if (s8 < 0) s8 = 0; if (s8 > 72) s8 = 72;
        int s4 = ((((j & ~3) * 95) / 191) - 6) & ~7;   // 8-aligned (16B fp16)
        if (s4 < 0) s4 = 0; if (s4 > 72) s4 = 72;
        if ((j & 7) == 0) T.S8[j >> 3] = s8;
        if ((j & 3) == 0) T.S4[j >> 2] = s4;
        for (int tt = 0; tt < BW; ++tt) {
            float mv = (float)m[s8 + tt];
            T.WB8T[j >> 3][tt][j & 7] = mv;
            T.WB4 [j >> 2][tt][j & 3] = mv;
        }
        for (int tp = 0; tp < 12; ++tp)
            T.WT12[j][tp] = cpackh2(m[s4 + 2 * tp], m[s4 + 2 * tp + 1]);
    }
    return T;
}

__device__ const Tables TAB = make_tables();

// ---------------- pass 1: x-expansion ----------------
// in f32 [4][96][9216] -> T1h fp16 [4][192][9216]; blockIdx.y = output oct.
template <int QUADS>
__global__ __launch_bounds__(256)
void pass_x_kernel(const float4* __restrict__ in, uint2* __restrict__ outh) {
    int g  = blockIdx.x * 256 + threadIdx.x;
    int o  = g / QUADS;
    int q  = g - o * QUADS;
    int jo = blockIdx.y;
    int S  = TAB.S8[jo];
    const float4* ip = in + ((size_t)o * N_IN + S) * QUADS + q;
    const float4* wp = (const float4*)(&TAB.WB8T[jo][0][0]);  // wave-uniform
    float4 acc[8];
#pragma unroll
    for (int jj = 0; jj < 8; ++jj) acc[jj] = make_float4(0.f, 0.f, 0.f, 0.f);
#pragma unroll
    for (int t = 0; t < BW; ++t) {
        float4 v   = ip[(size_t)t * QUADS];
        float4 wlo = wp[2 * t];
        float4 whi = wp[2 * t + 1];
        fma4(acc[0], wlo.x, v); fma4(acc[1], wlo.y, v);
        fma4(acc[2], wlo.z, v); fma4(acc[3], wlo.w, v);
        fma4(acc[4], whi.x, v); fma4(acc[5], whi.y, v);
        fma4(acc[6], whi.z, v); fma4(acc[7], whi.w, v);
    }
    uint2* op = outh + ((size_t)o * N_OUT + jo * 8) * QUADS + q;
#pragma unroll
    for (int jj = 0; jj < 8; ++jj) {
        uint2 pk;
        pk.x = packh2(acc[jj].x, acc[jj].y);
        pk.y = packh2(acc[jj].z, acc[jj].w);
        op[(size_t)jj * QUADS] = pk;
    }
}

// ---------------- fused pass 2+3 ----------------
// Block (o, zh): slab o = (bc,x'), output [192 y'][96 z' @ zh*96] from fp16
// slab cols [zbase, zbase+64). LDS: Sl (slab) + Ty (y-expanded) + WLs
// (pre-packed stage-B weights, persistent). Per y'-half h: stage A y-expand
// Sl->Ty, stage B z-expand Ty->global (dot2, NT stores).
// (384,6): cap 85 VGPR. Safe now — weights are phase-local LDS reads, natural
// pressure ~70 (r6's spill was capping a kernel that NEEDED ~100+).
__global__ __launch_bounds__(384, 6)
void pass_yz_kernel(const unsigned short* __restrict__ T1h,
                    float* __restrict__ out) {
    __shared__ unsigned short Sl[N_IN * SP2];   // 13.8 KB
    __shared__ unsigned short Ty[N_IN * SP2];   // 13.8 KB
    __shared__ unsigned int   WLs[N_IN * 13];   // 4.9 KB, rows padded 12->13
    int bid   = blockIdx.x;
    int o     = bid >> 1;
    int zh    = bid & 1;
    int zbase = zh ? 32 : 0;
    int tid   = threadIdx.x;  // 0..383

    // Stage 0a: slab cols [zbase, zbase+64): 96 rows x 64 halfs, uint4 loads
    {
        const unsigned short* sb = T1h + (size_t)o * N_IN * N_IN + zbase;
#pragma unroll
        for (int it = 0; it < 2; ++it) {
            int f = it * 384 + tid;      // 0..767
            int r = f >> 3, c = f & 7;
            *(uint4*)(Sl + r * SP2 + c * 8) = *(const uint4*)(sb + r * N_IN + c * 8);
        }
    }
    // Stage 0b: stage this zh-half of WT12 into WLs (coalesced contiguous)
    {
        const unsigned int* src = &TAB.WT12[zh * 96][0];   // 1152 u32
        for (int k = tid; k < 96 * 12; k += 384) {
            int r = k / 12, t = k - r * 12;
            WLs[r * 13 + t] = src[k];
        }
    }

    // thread roles
    int jp = tid % 48;        // stage B: z'-pair
    int yg = tid / 48;        // stage B: y'-group (12 rows each)
    int jA = zh * 96 + jp * 2;
    int c0 = TAB.S4[jA >> 2] - zbase;  // local 8-aligned window start
    int zq = tid & 15;        // stage A: z-quad
    int rq = tid >> 4;        // stage A: row-quad (0..23)

    __syncthreads();

    for (int h = 0; h < 2; ++h) {
        // ---- Stage A: y-expand rows [h*96, h*96+96) into Ty ----
        {
            int Sg = TAB.S8[(h * 96 + rq * 4) >> 3];
            const float4* wp = (const float4*)(&TAB.WB4[h * 24 + rq][0][0]);
            const unsigned short* sp = Sl + Sg * SP2 + zq * 4;
            float4 a0 = make_float4(0.f,0.f,0.f,0.f), a1 = a0, a2 = a0, a3 = a0;
#pragma unroll
            for (int t = 0; t < BW; ++t) {
                uint2 hv = *(const uint2*)(sp + (size_t)t * SP2);
                h2 p0 = __builtin_bit_cast(h2, hv.x);
                h2 p1 = __builtin_bit_cast(h2, hv.y);
                float4 v = make_float4((float)p0.x, (float)p0.y,
                                       (float)p1.x, (float)p1.y);
                float4 wq = wp[t];
                fma4(a0, wq.x, v); fma4(a1, wq.y, v);
                fma4(a2, wq.z, v); fma4(a3, wq.w, v);
            }
            unsigned short* ty = Ty + (rq * 4) * SP2 + zq * 4;
            uint2 pk;
            pk.x = packh2(a0.x, a0.y); pk.y = packh2(a0.z, a0.w);
            *(uint2*)(ty + 0 * SP2) = pk;
            pk.x = packh2(a1.x, a1.y); pk.y = packh2(a1.z, a1.w);
            *(uint2*)(ty + 1 * SP2) = pk;
            pk.x = packh2(a2.x, a2.y); pk.y = packh2(a2.z, a2.w);
            *(uint2*)(ty + 2 * SP2) = pk;
            pk.x = packh2(a3.x, a3.y); pk.y = packh2(a3.z, a3.w);
            *(uint2*)(ty + 3 * SP2) = pk;
        }
        __syncthreads();

        // ---- Stage B: z-expand 12 rows x 2 z' per thread (NT stores) ----
        {
            unsigned int wA[12], wB[12];
            const unsigned int* wra = WLs + (jp * 2) * 13;
#pragma unroll
            for (int tp = 0; tp < 12; ++tp) {
                wA[tp] = wra[tp];
                wB[tp] = wra[13 + tp];
            }
            float* ob = out + (((size_t)o * N_OUT + h * 96 + yg * 12) * N_OUT)
                        + zh * 96 + jp * 2;
#pragma unroll
            for (int rr = 0; rr < 12; ++rr) {
                const uint4* tq = (const uint4*)(Ty + (yg * 12 + rr) * SP2 + c0);
                uint4 q0 = tq[0], q1 = tq[1], q2 = tq[2];
                float sA = 0.f, sB = 0.f;
                sA = dot2h(wA[0],  q0.x, sA); sB = dot2h(wB[0],  q0.x, sB);
                sA = dot2h(wA[1],  q0.y, sA); sB = dot2h(wB[1],  q0.y, sB);
                sA = dot2h(wA[2],  q0.z, sA); sB = dot2h(wB[2],  q0.z, sB);
                sA = dot2h(wA[3],  q0.w, sA); sB = dot2h(wB[3],  q0.w, sB);
                sA = dot2h(wA[4],  q1.x, sA); sB = dot2h(wB[4],  q1.x, sB);
                sA = dot2h(wA[5],  q1.y, sA); sB = dot2h(wB[5],  q1.y, sB);
                sA = dot2h(wA[6],  q1.z, sA); sB = dot2h(wB[6],  q1.z, sB);
                sA = dot2h(wA[7],  q1.w, sA); sB = dot2h(wB[7],  q1.w, sB);
                sA = dot2h(wA[8],  q2.x, sA); sB = dot2h(wB[8],  q2.x, sB);
                sA = dot2h(wA[9],  q2.y, sA); sB = dot2h(wB[9],  q2.y, sB);
                sA = dot2h(wA[10], q2.z, sA); sB = dot2h(wB[10], q2.z, sB);
                sA = dot2h(wA[11], q2.w, sA); sB = dot2h(wB[11], q2.w, sB);
                float2 st; st.x = sA; st.y = sB;
                __builtin_nontemporal_store(
                    __builtin_bit_cast(unsigned long long, st),
                    (unsigned long long*)(ob + (size_t)rr * N_OUT));
            }
        }
        __syncthreads();  // Ty reused by next h's stage A
    }
}

extern "C" void kernel_launch(void* const* d_in, const int* in_sizes, int n_in,
                              void* d_out, int out_size, void* d_ws, size_t ws_size,
                              hipStream_t stream) {
    const float* in  = (const float*)d_in[0];
    float*       out = (float*)d_out;
    unsigned short* T1h = (unsigned short*)d_ws;  // [4][192][9216] fp16 = 14.2 MB

    // Pass 1: x-axis. in [4][96][2304 f4] -> T1h [4][192][2304 h4]
    {
        dim3 g(4 * 2304 / 256, BW, 1);  // (36, 24)
        pass_x_kernel<2304><<<g, 256, 0, stream>>>((const float4*)in, (uint2*)T1h);
    }
    // Fused pass 2+3: T1h [768 slabs][96][96] -> out [768][192][192]
    pass_yz_kernel<<<768 * 2, 384, 0, stream>>>(T1h, out);
}

// Round 10
// 64.122 us; speedup vs baseline: 2.0837x; 2.0837x over previous
//
#include <hip/hip_runtime.h>
#include <math.h>

#define N_IN  96
#define N_OUT 192
#define BW    24    // truncated band window width
#define SP2   72    // LDS row stride in halfs (144B: 16B-aligned, 4-bank row skew)

typedef _Float16 h2 __attribute__((ext_vector_type(2)));

__device__ __forceinline__ float dot2h(unsigned int w, unsigned int v, float acc) {
#if __has_builtin(__builtin_amdgcn_fdot2)
    return __builtin_amdgcn_fdot2(__builtin_bit_cast(h2, w),
                                  __builtin_bit_cast(h2, v), acc, false);
#else
    h2 a = __builtin_bit_cast(h2, w), b = __builtin_bit_cast(h2, v);
    return acc + (float)a.x * (float)b.x + (float)a.y * (float)b.y;
#endif
}

__device__ __forceinline__ unsigned int packh2(float a, float b) {
    h2 h; h.x = (_Float16)a; h.y = (_Float16)b;
    return __builtin_bit_cast(unsigned int, h);
}

__device__ __forceinline__ void fma4(float4& a, float w, const float4& v) {
    a.x += w * v.x; a.y += w * v.y; a.z += w * v.z; a.w += w * v.w;
}

// ---------------- compile-time weight tables ----------------
// M = B_resize(192x96) * A^-1, A = cubic-spline interp operator with dct2
// boundary (tridiag: diag 2/3, 5/6 at ends, off-diag 1/6). Constexpr Thomas
// solve; stage-B weights pre-packed to half2 u32 at compile time.
struct Tables {
    float        WB8T[24][24][8];   // pass-x: [oct][tap][jj], window S8[oct]
    float        WB4 [48][24][4];   // stage-A: [j-quad][tap][jj], window S8
    unsigned int WT12[192][12];     // stage-B: [j][tap-pair] half2, window S4[j/4]
    int          S8[24];
    int          S4[48];
};

constexpr int cfold(int idx, int n) {
    int p = 2 * n;
    int m = idx % p; if (m < 0) m += p;
    return (m >= n) ? (p - 1 - m) : m;
}

constexpr unsigned int cpackh2(double a, double b) {
    _Float16 ha = (_Float16)(float)a;
    _Float16 hb = (_Float16)(float)b;
    unsigned short ua = __builtin_bit_cast(unsigned short, ha);
    unsigned short ub = __builtin_bit_cast(unsigned short, hb);
    return (unsigned int)ua | ((unsigned int)ub << 16);
}

constexpr Tables make_tables() {
    Tables T{};
    double cp[N_IN] = {}, minv[N_IN] = {};
    const double a = 1.0 / 6.0;
    minv[0] = 1.0 / (5.0 / 6.0);
    cp[0]   = a * minv[0];
    for (int i = 1; i < N_IN; ++i) {
        double bi = (i == N_IN - 1) ? (5.0 / 6.0) : (2.0 / 3.0);
        minv[i] = 1.0 / (bi - a * cp[i - 1]);
        cp[i]   = a * minv[i];
    }
    for (int j = 0; j < N_OUT; ++j) {
        double x = (double)j * 95.0 / 191.0;
        int    b = (int)x;
        double t = x - (double)b;
        double t2 = t * t, t3 = t2 * t;
        double w0 = (1.0 - t) * (1.0 - t) * (1.0 - t) / 6.0;
        double w1 = (3.0 * t3 - 6.0 * t2 + 4.0) / 6.0;
        double w2 = (-3.0 * t3 + 3.0 * t2 + 3.0 * t + 1.0) / 6.0;
        double w3 = t3 / 6.0;
        double r[N_IN] = {};
        r[cfold(b - 1, N_IN)] += w0;
        r[cfold(b,     N_IN)] += w1;
        r[cfold(b + 1, N_IN)] += w2;
        r[cfold(b + 2, N_IN)] += w3;
        double m[N_IN] = {};
        double dp = 0.0;
        for (int i = 0; i < N_IN; ++i) {
            dp = (i == 0) ? r[0] * minv[0] : (r[i] - a * dp) * minv[i];
            m[i] = dp;
        }
        double xv = 0.0;
        for (int i = N_IN - 1; i >= 0; --i) {
            xv = (i == N_IN - 1) ? m[i] : (m[i] - cp[i] * xv);
            m[i] = xv;
        }
        int s8 = ((j & ~7) * 95) / 191 - 9;
        if (s8 < 0) s8 = 0; if (s8 > 72) s8 = 72;
        int s4 = ((((j & ~3) * 95) / 191) - 6) & ~7;   // 8-aligned (16B fp16)
        if (s4 < 0) s4 = 0; if (s4 > 72) s4 = 72;
        if ((j & 7) == 0) T.S8[j >> 3] = s8;
        if ((j & 3) == 0) T.S4[j >> 2] = s4;
        for (int tt = 0; tt < BW; ++tt) {
            float mv = (float)m[s8 + tt];
            T.WB8T[j >> 3][tt][j & 7] = mv;
            T.WB4 [j >> 2][tt][j & 3] = mv;
        }
        for (int tp = 0; tp < 12; ++tp)
            T.WT12[j][tp] = cpackh2(m[s4 + 2 * tp], m[s4 + 2 * tp + 1]);
    }
    return T;
}

__device__ const Tables TAB = make_tables();

// ---------------- pass 1: x-expansion ----------------
// in f32 [4][96][9216] -> T1h fp16 [4][192][9216]; blockIdx.y = output oct.
template <int QUADS>
__global__ __launch_bounds__(256)
void pass_x_kernel(const float4* __restrict__ in, uint2* __restrict__ outh) {
    int g  = blockIdx.x * 256 + threadIdx.x;
    int o  = g / QUADS;
    int q  = g - o * QUADS;
    int jo = blockIdx.y;
    int S  = TAB.S8[jo];
    const float4* ip = in + ((size_t)o * N_IN + S) * QUADS + q;
    const float4* wp = (const float4*)(&TAB.WB8T[jo][0][0]);  // wave-uniform
    float4 acc[8];
#pragma unroll
    for (int jj = 0; jj < 8; ++jj) acc[jj] = make_float4(0.f, 0.f, 0.f, 0.f);
#pragma unroll
    for (int t = 0; t < BW; ++t) {
        float4 v   = ip[(size_t)t * QUADS];
        float4 wlo = wp[2 * t];
        float4 whi = wp[2 * t + 1];
        fma4(acc[0], wlo.x, v); fma4(acc[1], wlo.y, v);
        fma4(acc[2], wlo.z, v); fma4(acc[3], wlo.w, v);
        fma4(acc[4], whi.x, v); fma4(acc[5], whi.y, v);
        fma4(acc[6], whi.z, v); fma4(acc[7], whi.w, v);
    }
    uint2* op = outh + ((size_t)o * N_OUT + jo * 8) * QUADS + q;
#pragma unroll
    for (int jj = 0; jj < 8; ++jj) {
        uint2 pk;
        pk.x = packh2(acc[jj].x, acc[jj].y);
        pk.y = packh2(acc[jj].z, acc[jj].w);
        op[(size_t)jj * QUADS] = pk;
    }
}

// ---------------- fused pass 2+3, quarter blocks ----------------
// Block = (o, zh, h): slab o = (bc,x'), z'-half zh, y'-half h. Produces
// out[o][h*96 + 0..95][zh*96 + 0..95]. Stage A reads the fp16 slab DIRECTLY
// from global (12 KB footprint, L2-resident, ~6x intra-block reuse) and
// y-expands into Ty (only LDS buffer). ONE barrier. Stage B z-expands from
// Ty with compile-time-packed half2 weights (9 KB L2-hot table), NT stores.
// Plain __launch_bounds__ — the min-waves arg spilled to scratch 3x in this
// session (r6/r7/r9: VGPR_Count=40, +150-250 MB HBM traffic).
__global__ __launch_bounds__(384)
void pass_yz_kernel(const unsigned short* __restrict__ T1h,
                    float* __restrict__ out) {
    __shared__ unsigned short Ty[N_IN * SP2];   // 13.8 KB
    int bid   = blockIdx.x;            // 0..3071
    int o     = bid >> 2;
    int zh    = (bid >> 1) & 1;
    int h     = bid & 1;
    int zbase = zh ? 32 : 0;
    int tid   = threadIdx.x;           // 0..383

    // ---- Stage A: y-expand rows [h*96, h*96+96) from global into Ty ----
    {
        int zq = tid & 15;             // z-quad (4 halfs)
        int rq = tid >> 4;             // row-quad 0..23
        int Sg = TAB.S8[(h * 96 + rq * 4) >> 3];
        const float4* wp = (const float4*)(&TAB.WB4[h * 24 + rq][0][0]);
        const unsigned short* sp =
            T1h + (size_t)o * N_IN * N_IN + (size_t)Sg * N_IN + zbase + zq * 4;
        float4 a0 = make_float4(0.f,0.f,0.f,0.f), a1 = a0, a2 = a0, a3 = a0;
#pragma unroll
        for (int t = 0; t < BW; ++t) {
            uint2 hv = *(const uint2*)(sp + (size_t)t * N_IN);
            h2 p0 = __builtin_bit_cast(h2, hv.x);
            h2 p1 = __builtin_bit_cast(h2, hv.y);
            float4 v = make_float4((float)p0.x, (float)p0.y,
                                   (float)p1.x, (float)p1.y);
            float4 wq = wp[t];
            fma4(a0, wq.x, v); fma4(a1, wq.y, v);
            fma4(a2, wq.z, v); fma4(a3, wq.w, v);
        }
        unsigned short* ty = Ty + (rq * 4) * SP2 + zq * 4;
        uint2 pk;
        pk.x = packh2(a0.x, a0.y); pk.y = packh2(a0.z, a0.w);
        *(uint2*)(ty + 0 * SP2) = pk;
        pk.x = packh2(a1.x, a1.y); pk.y = packh2(a1.z, a1.w);
        *(uint2*)(ty + 1 * SP2) = pk;
        pk.x = packh2(a2.x, a2.y); pk.y = packh2(a2.z, a2.w);
        *(uint2*)(ty + 2 * SP2) = pk;
        pk.x = packh2(a3.x, a3.y); pk.y = packh2(a3.z, a3.w);
        *(uint2*)(ty + 3 * SP2) = pk;
    }
    __syncthreads();

    // ---- Stage B: z-expand 12 rows x 2 z' per thread (NT stores) ----
    {
        int jp = tid % 48;             // z'-pair
        int yg = tid / 48;             // y'-group (12 rows)
        int jA = zh * 96 + jp * 2;
        int c0 = TAB.S4[jA >> 2] - zbase;
        unsigned int wA[12], wB[12];
        {
            const uint4* wpa = (const uint4*)(&TAB.WT12[jA][0]);
            const uint4* wpb = (const uint4*)(&TAB.WT12[jA + 1][0]);
            uint4 wa0 = wpa[0], wa1 = wpa[1], wa2 = wpa[2];
            uint4 wb0 = wpb[0], wb1 = wpb[1], wb2 = wpb[2];
            wA[0]=wa0.x; wA[1]=wa0.y; wA[2]=wa0.z; wA[3]=wa0.w;
            wA[4]=wa1.x; wA[5]=wa1.y; wA[6]=wa1.z; wA[7]=wa1.w;
            wA[8]=wa2.x; wA[9]=wa2.y; wA[10]=wa2.z; wA[11]=wa2.w;
            wB[0]=wb0.x; wB[1]=wb0.y; wB[2]=wb0.z; wB[3]=wb0.w;
            wB[4]=wb1.x; wB[5]=wb1.y; wB[6]=wb1.z; wB[7]=wb1.w;
            wB[8]=wb2.x; wB[9]=wb2.y; wB[10]=wb2.z; wB[11]=wb2.w;
        }
        float* ob = out + (((size_t)o * N_OUT + h * 96 + yg * 12) * N_OUT)
                    + zh * 96 + jp * 2;
#pragma unroll
        for (int rr = 0; rr < 12; ++rr) {
            const uint4* tq = (const uint4*)(Ty + (yg * 12 + rr) * SP2 + c0);
            uint4 q0 = tq[0], q1 = tq[1], q2 = tq[2];
            float sA = 0.f, sB = 0.f;
            sA = dot2h(wA[0],  q0.x, sA); sB = dot2h(wB[0],  q0.x, sB);
            sA = dot2h(wA[1],  q0.y, sA); sB = dot2h(wB[1],  q0.y, sB);
            sA = dot2h(wA[2],  q0.z, sA); sB = dot2h(wB[2],  q0.z, sB);
            sA = dot2h(wA[3],  q0.w, sA); sB = dot2h(wB[3],  q0.w, sB);
            sA = dot2h(wA[4],  q1.x, sA); sB = dot2h(wB[4],  q1.x, sB);
            sA = dot2h(wA[5],  q1.y, sA); sB = dot2h(wB[5],  q1.y, sB);
            sA = dot2h(wA[6],  q1.z, sA); sB = dot2h(wB[6],  q1.z, sB);
            sA = dot2h(wA[7],  q1.w, sA); sB = dot2h(wB[7],  q1.w, sB);
            sA = dot2h(wA[8],  q2.x, sA); sB = dot2h(wB[8],  q2.x, sB);
            sA = dot2h(wA[9],  q2.y, sA); sB = dot2h(wB[9],  q2.y, sB);
            sA = dot2h(wA[10], q2.z, sA); sB = dot2h(wB[10], q2.z, sB);
            sA = dot2h(wA[11], q2.w, sA); sB = dot2h(wB[11], q2.w, sB);
            float2 st; st.x = sA; st.y = sB;
            __builtin_nontemporal_store(
                __builtin_bit_cast(unsigned long long, st),
                (unsigned long long*)(ob + (size_t)rr * N_OUT));
        }
    }
}

extern "C" void kernel_launch(void* const* d_in, const int* in_sizes, int n_in,
                              void* d_out, int out_size, void* d_ws, size_t ws_size,
                              hipStream_t stream) {
    const float* in  = (const float*)d_in[0];
    float*       out = (float*)d_out;
    unsigned short* T1h = (unsigned short*)d_ws;  // [4][192][9216] fp16 = 14.2 MB

    // Pass 1: x-axis. in [4][96][2304 f4] -> T1h [4][192][2304 h4]
    {
        dim3 g(4 * 2304 / 256, BW, 1);  // (36, 24)
        pass_x_kernel<2304><<<g, 256, 0, stream>>>((const float4*)in, (uint2*)T1h);
    }
    // Fused pass 2+3: T1h [768 slabs][96][96] -> out [768][192][192]
    // block = (slab, z'-half, y'-half)
    pass_yz_kernel<<<768 * 4, 384, 0, stream>>>(T1h, out);
}

// Round 12
// 58.545 us; speedup vs baseline: 2.2822x; 1.0953x over previous
//
#include <hip/hip_runtime.h>
#include <math.h>

#define N_IN  96
#define N_OUT 192
#define BW    24    // truncated band window width
#define SP2   104   // Ty row stride in halfs (208B: 16B-aligned, bank-spread)

typedef _Float16 h2 __attribute__((ext_vector_type(2)));
typedef float    f32x4 __attribute__((ext_vector_type(4)));

__device__ __forceinline__ float dot2h(unsigned int w, unsigned int v, float acc) {
#if __has_builtin(__builtin_amdgcn_fdot2)
    return __builtin_amdgcn_fdot2(__builtin_bit_cast(h2, w),
                                  __builtin_bit_cast(h2, v), acc, false);
#else
    h2 a = __builtin_bit_cast(h2, w), b = __builtin_bit_cast(h2, v);
    return acc + (float)a.x * (float)b.x + (float)a.y * (float)b.y;
#endif
}

__device__ __forceinline__ unsigned int packh2(float a, float b) {
    h2 h; h.x = (_Float16)a; h.y = (_Float16)b;
    return __builtin_bit_cast(unsigned int, h);
}

__device__ __forceinline__ void fma4(float4& a, float w, const float4& v) {
    a.x += w * v.x; a.y += w * v.y; a.z += w * v.z; a.w += w * v.w;
}

// ---------------- compile-time weight tables ----------------
// M = B_resize(192x96) * A^-1, A = cubic-spline interp operator with dct2
// boundary (tridiag: diag 2/3, 5/6 at ends, off-diag 1/6). Constexpr Thomas
// solve; stage-B weights pre-packed to half2 u32 at compile time.
struct Tables {
    float        WB8T[24][24][8];   // pass-x: [oct][tap][jj], window S8[oct]
    float        WB4 [48][24][4];   // stage-A: [j-quad][tap][jj], window S8
    unsigned int WT12[192][12];     // stage-B: [j][tap-pair] half2, window S4[j/4]
    int          S8[24];
    int          S4[48];
};

constexpr int cfold(int idx, int n) {
    int p = 2 * n;
    int m = idx % p; if (m < 0) m += p;
    return (m >= n) ? (p - 1 - m) : m;
}

constexpr unsigned int cpackh2(double a, double b) {
    _Float16 ha = (_Float16)(float)a;
    _Float16 hb = (_Float16)(float)b;
    unsigned short ua = __builtin_bit_cast(unsigned short, ha);
    unsigned short ub = __builtin_bit_cast(unsigned short, hb);
    return (unsigned int)ua | ((unsigned int)ub << 16);
}

constexpr Tables make_tables() {
    Tables T{};
    double cp[N_IN] = {}, minv[N_IN] = {};
    const double a = 1.0 / 6.0;
    minv[0] = 1.0 / (5.0 / 6.0);
    cp[0]   = a * minv[0];
    for (int i = 1; i < N_IN; ++i) {
        double bi = (i == N_IN - 1) ? (5.0 / 6.0) : (2.0 / 3.0);
        minv[i] = 1.0 / (bi - a * cp[i - 1]);
        cp[i]   = a * minv[i];
    }
    for (int j = 0; j < N_OUT; ++j) {
        double x = (double)j * 95.0 / 191.0;
        int    b = (int)x;
        double t = x - (double)b;
        double t2 = t * t, t3 = t2 * t;
        double w0 = (1.0 - t) * (1.0 - t) * (1.0 - t) / 6.0;
        double w1 = (3.0 * t3 - 6.0 * t2 + 4.0) / 6.0;
        double w2 = (-3.0 * t3 + 3.0 * t2 + 3.0 * t + 1.0) / 6.0;
        double w3 = t3 / 6.0;
        double r[N_IN] = {};
        r[cfold(b - 1, N_IN)] += w0;
        r[cfold(b,     N_IN)] += w1;
        r[cfold(b + 1, N_IN)] += w2;
        r[cfold(b + 2, N_IN)] += w3;
        double m[N_IN] = {};
        double dp = 0.0;
        for (int i = 0; i < N_IN; ++i) {
            dp = (i == 0) ? r[0] * minv[0] : (r[i] - a * dp) * minv[i];
            m[i] = dp;
        }
        double xv = 0.0;
        for (int i = N_IN - 1; i >= 0; --i) {
            xv = (i == N_IN - 1) ? m[i] : (m[i] - cp[i] * xv);
            m[i] = xv;
        }
        int s8 = ((j & ~7) * 95) / 191 - 9;
        if (s8 < 0) s8 = 0; if (s8 > 72) s8 = 72;
        int s4 = ((((j & ~3) * 95) / 191) - 6) & ~7;   // 8-aligned (16B fp16)
        if (s4 < 0) s4 = 0; if (s4 > 72) s4 = 72;
        if ((j & 7) == 0) T.S8[j >> 3] = s8;
        if ((j & 3) == 0) T.S4[j >> 2] = s4;
        for (int tt = 0; tt < BW; ++tt) {
            float mv = (float)m[s8 + tt];
            T.WB8T[j >> 3][tt][j & 7] = mv;
            T.WB4 [j >> 2][tt][j & 3] = mv;
        }
        for (int tp = 0; tp < 12; ++tp)
            T.WT12[j][tp] = cpackh2(m[s4 + 2 * tp], m[s4 + 2 * tp + 1]);
    }
    return T;
}

__device__ const Tables TAB = make_tables();

__device__ __forceinline__ float dot12(const uint4& w0, const uint4& w1,
                                       const uint4& w2, const uint4& q0,
                                       const uint4& q1, const uint4& q2) {
    float s = 0.f;
    s = dot2h(w0.x, q0.x, s); s = dot2h(w0.y, q0.y, s);
    s = dot2h(w0.z, q0.z, s); s = dot2h(w0.w, q0.w, s);
    s = dot2h(w1.x, q1.x, s); s = dot2h(w1.y, q1.y, s);
    s = dot2h(w1.z, q1.z, s); s = dot2h(w1.w, q1.w, s);
    s = dot2h(w2.x, q2.x, s); s = dot2h(w2.y, q2.y, s);
    s = dot2h(w2.z, q2.z, s); s = dot2h(w2.w, q2.w, s);
    return s;
}

// ---------------- pass 1: x-expansion ----------------
// in f32 [4][96][9216] -> T1h fp16 [4][192][9216]; blockIdx.y = output oct.
template <int QUADS>
__global__ __launch_bounds__(256)
void pass_x_kernel(const float4* __restrict__ in, uint2* __restrict__ outh) {
    int g  = blockIdx.x * 256 + threadIdx.x;
    int o  = g / QUADS;
    int q  = g - o * QUADS;
    int jo = blockIdx.y;
    int S  = TAB.S8[jo];
    const float4* ip = in + ((size_t)o * N_IN + S) * QUADS + q;
    const float4* wp = (const float4*)(&TAB.WB8T[jo][0][0]);  // wave-uniform
    float4 acc[8];
#pragma unroll
    for (int jj = 0; jj < 8; ++jj) acc[jj] = make_float4(0.f, 0.f, 0.f, 0.f);
#pragma unroll
    for (int t = 0; t < BW; ++t) {
        float4 v   = ip[(size_t)t * QUADS];
        float4 wlo = wp[2 * t];
        float4 whi = wp[2 * t + 1];
        fma4(acc[0], wlo.x, v); fma4(acc[1], wlo.y, v);
        fma4(acc[2], wlo.z, v); fma4(acc[3], wlo.w, v);
        fma4(acc[4], whi.x, v); fma4(acc[5], whi.y, v);
        fma4(acc[6], whi.z, v); fma4(acc[7], whi.w, v);
    }
    uint2* op = outh + ((size_t)o * N_OUT + jo * 8) * QUADS + q;
#pragma unroll
    for (int jj = 0; jj < 8; ++jj) {
        uint2 pk;
        pk.x = packh2(acc[jj].x, acc[jj].y);
        pk.y = packh2(acc[jj].z, acc[jj].w);
        op[(size_t)jj * QUADS] = pk;
    }
}

// ---------------- fused pass 2+3, half blocks ----------------
// Block = (o, h): slab o = (bc,x'), y'-half h. Produces out[o][h*96+0..95][:]
// — FULL 192-wide rows so stage-B stores are 16B/lane and lanes 0..47 cover
// one whole 768B row contiguously (store-BW was the r10 suspect).
// Stage A reads the fp16 slab directly from global (L2-resident, reused
// across o's 2 blocks), y-expands ALL 96 z-cols into Ty. ONE barrier.
// Stage B z-expands 96->192 with compile-time-packed half2 weights.
// Plain __launch_bounds__ — min-waves arg spilled to scratch 3x (r6/r7/r9).
__global__ __launch_bounds__(384)
void pass_yz_kernel(const unsigned short* __restrict__ T1h,
                    float* __restrict__ out) {
    __shared__ unsigned short Ty[N_IN * SP2];   // 20 KB
    int bid = blockIdx.x;              // 0..1535
    int o   = bid >> 1;
    int h   = bid & 1;
    int tid = threadIdx.x;             // 0..383

    // ---- Stage A: y-expand rows [h*96, h*96+96), all 96 z-cols, into Ty ----
    // 576 tasks (24 row-quads x 24 col-quads); threads 0..191 take 2 tasks.
    for (int task = tid; task < 576; task += 384) {
        int rq = task / 24;            // row-quad 0..23
        int zq = task - rq * 24;       // col-quad 0..23
        int Sg = TAB.S8[(h * 96 + rq * 4) >> 3];
        const float4* wp = (const float4*)(&TAB.WB4[h * 24 + rq][0][0]);
        const unsigned short* sp =
            T1h + (size_t)o * N_IN * N_IN + (size_t)Sg * N_IN + zq * 4;
        float4 a0 = make_float4(0.f,0.f,0.f,0.f), a1 = a0, a2 = a0, a3 = a0;
#pragma unroll
        for (int t = 0; t < BW; ++t) {
            uint2 hv = *(const uint2*)(sp + (size_t)t * N_IN);
            h2 p0 = __builtin_bit_cast(h2, hv.x);
            h2 p1 = __builtin_bit_cast(h2, hv.y);
            float4 v = make_float4((float)p0.x, (float)p0.y,
                                   (float)p1.x, (float)p1.y);
            float4 wq = wp[t];
            fma4(a0, wq.x, v); fma4(a1, wq.y, v);
            fma4(a2, wq.z, v); fma4(a3, wq.w, v);
        }
        unsigned short* ty = Ty + (rq * 4) * SP2 + zq * 4;
        uint2 pk;
        pk.x = packh2(a0.x, a0.y); pk.y = packh2(a0.z, a0.w);
        *(uint2*)(ty + 0 * SP2) = pk;
        pk.x = packh2(a1.x, a1.y); pk.y = packh2(a1.z, a1.w);
        *(uint2*)(ty + 1 * SP2) = pk;
        pk.x = packh2(a2.x, a2.y); pk.y = packh2(a2.z, a2.w);
        *(uint2*)(ty + 2 * SP2) = pk;
        pk.x = packh2(a3.x, a3.y); pk.y = packh2(a3.z, a3.w);
        *(uint2*)(ty + 3 * SP2) = pk;
    }
    __syncthreads();

    // ---- Stage B: thread = (yg 0..7, jq 0..47): 12 rows x 4 z' (one S4
    // quad, shared 8-aligned window). 16B NT stores; lanes 0..47 = full row.
    {
        int jq = tid % 48;
        int yg = tid / 48;
        int c0 = TAB.S4[jq];
        const uint4* wp0 = (const uint4*)(&TAB.WT12[jq * 4 + 0][0]);
        const uint4* wp1 = (const uint4*)(&TAB.WT12[jq * 4 + 1][0]);
        const uint4* wp2 = (const uint4*)(&TAB.WT12[jq * 4 + 2][0]);
        const uint4* wp3 = (const uint4*)(&TAB.WT12[jq * 4 + 3][0]);
        uint4 w00 = wp0[0], w01 = wp0[1], w02 = wp0[2];
        uint4 w10 = wp1[0], w11 = wp1[1], w12 = wp1[2];
        uint4 w20 = wp2[0], w21 = wp2[1], w22 = wp2[2];
        uint4 w30 = wp3[0], w31 = wp3[1], w32 = wp3[2];
        float* ob = out + (((size_t)o * N_OUT + h * 96 + yg * 12) * N_OUT)
                    + jq * 4;
#pragma unroll
        for (int rr = 0; rr < 12; ++rr) {
            const uint4* tq = (const uint4*)(Ty + (yg * 12 + rr) * SP2 + c0);
            uint4 q0 = tq[0], q1 = tq[1], q2 = tq[2];
            f32x4 st;
            st.x = dot12(w00, w01, w02, q0, q1, q2);
            st.y = dot12(w10, w11, w12, q0, q1, q2);
            st.z = dot12(w20, w21, w22, q0, q1, q2);
            st.w = dot12(w30, w31, w32, q0, q1, q2);
            __builtin_nontemporal_store(st, (f32x4*)(ob + (size_t)rr * N_OUT));
        }
    }
}

extern "C" void kernel_launch(void* const* d_in, const int* in_sizes, int n_in,
                              void* d_out, int out_size, void* d_ws, size_t ws_size,
                              hipStream_t stream) {
    const float* in  = (const float*)d_in[0];
    float*       out = (float*)d_out;
    unsigned short* T1h = (unsigned short*)d_ws;  // [4][192][9216] fp16 = 14.2 MB

    // Pass 1: x-axis. in [4][96][2304 f4] -> T1h [4][192][2304 h4]
    {
        dim3 g(4 * 2304 / 256, BW, 1);  // (36, 24)
        pass_x_kernel<2304><<<g, 256, 0, stream>>>((const float4*)in, (uint2*)T1h);
    }
    // Fused pass 2+3: T1h [768 slabs][96][96] -> out [768][192][192]
    // block = (slab, y'-half)
    pass_yz_kernel<<<768 * 2, 384, 0, stream>>>(T1h, out);
}